// Round 16
// baseline (263.653 us; speedup 1.0000x reference)
//
#include <hip/hip_runtime.h>

#define DIM 7
#define HID 128
#define CHOL 28

#define GRID_A 512
#define ITER_A 8           // 512 blocks * 16 waves * 2 elem * 8 iter = 131072
#define GRID_B 256
#define ITER_B 4           // 256 blocks * 8 waves * 16 elem * 4 iter = 131072

// sched_barrier mask: ALU|VALU|SALU|MFMA|VMEM may cross; DS blocked (per-wave phase ordering).
#define PHASE_FENCE() __builtin_amdgcn_sched_barrier(0x7F)

typedef float    f32x4  __attribute__((ext_vector_type(4)));
typedef short    bf16x8 __attribute__((ext_vector_type(8)));
typedef unsigned uint4v __attribute__((ext_vector_type(4)));
typedef unsigned uint2v __attribute__((ext_vector_type(2)));

__device__ __forceinline__ float tanh_f(float x){ float e=__expf(2.f*x); return 1.f - 2.f/(e+1.f); }
__device__ __forceinline__ float sig_f(float x){ return 1.f/(1.f+__expf(-x)); }
__device__ __forceinline__ float sp_f(float x){ return fmaxf(x,0.f) + __logf(1.f+__expf(-fabsf(x))); }

__device__ __forceinline__ unsigned short f2b(float v){
  unsigned u = __float_as_uint(v);
  u += 0x7FFFu + ((u>>16)&1u);          // RNE to bf16
  return (unsigned short)(u>>16);
}
// pack two f32 -> (bf16(a) | bf16(b)<<16), RNE
__device__ __forceinline__ unsigned pk2(float a, float b){
  unsigned ua = __float_as_uint(a), ub = __float_as_uint(b);
  ua += 0x7FFFu + ((ua>>16)&1u);
  ub += 0x7FFFu + ((ub>>16)&1u);
  return (ua>>16) | (ub & 0xFFFF0000u);
}
__device__ __forceinline__ float b2f(unsigned short v){
  return __uint_as_float(((unsigned)v)<<16);
}
__device__ __forceinline__ bf16x8 as_bf(uint4v u){ union { uint4v a; bf16x8 f; } x; x.a=u; return x.f; }

// ---- ws layout (u32): [0,8192) W2frag ; [8192,10240) W3frag ; [10240,18432) dW2frag ;
//                       [18432,20480) dW3frag   (80 KB total)
// frag order: u32 idx = (frag_id*64 + lane)*4 + i2 ; B[k][col], k = 32s+8*(l>>4)+2*i2(+1), col = 16t+(l&15)
// (A-frags use the SAME (group,elem)->k map, so layer-2/3 are correct for any HW intra-lane k order.)
__global__ void setup_frags(const float* __restrict__ mW2, const float* __restrict__ mW3,
                            const float* __restrict__ dW2, const float* __restrict__ dW3,
                            unsigned* __restrict__ ws){
  int idx = blockIdx.x*256 + threadIdx.x;
  if (idx < 8192) {
    int i2 = idx&3, f = idx>>2, l = f&63, st = f>>6;
    int s = st>>3, t = st&7;
    int k = 32*s + 8*(l>>4) + 2*i2, col = 16*t + (l&15);
    ws[idx] = pk2(mW2[k*HID+col], mW2[(k+1)*HID+col]);
  } else if (idx < 10240) {
    int j = idx-8192; int i2=j&3, f=j>>2, l=f&63, st=f>>6;
    int s = st>>1, t = st&1;
    int k = 32*s + 8*(l>>4) + 2*i2, col = 16*t + (l&15);
    float v0 = (col<CHOL) ? mW3[k*CHOL+col] : 0.f;
    float v1 = (col<CHOL) ? mW3[(k+1)*CHOL+col] : 0.f;
    ws[idx] = pk2(v0,v1);
  } else if (idx < 18432) {
    int j = idx-10240; int i2=j&3, f=j>>2, l=f&63, st=f>>6;
    int s = st>>3, t = st&7;
    int k = 32*s + 8*(l>>4) + 2*i2, col = 16*t + (l&15);
    ws[idx] = pk2(dW2[k*HID+col], dW2[(k+1)*HID+col]);
  } else if (idx < 20480) {
    int j = idx-18432; int i2=j&3, f=j>>2, l=f&63, st=f>>6;
    int s = st>>1, t = st&1;
    int k = 32*s + 8*(l>>4) + 2*i2, col = 16*t + (l&15);
    float v0 = (col<CHOL) ? dW3[k*CHOL+col] : 0.f;
    float v1 = (col<CHOL) ? dW3[(k+1)*CHOL+col] : 0.f;
    ws[idx] = pk2(v0,v1);
  }
}

// ---------------- Kernel A: ONE 16-wave block per CU; W2+W3 in shared LDS -------------------
// 1024 threads = 16 waves co-resident -> 4 waves/SIMD. A 16-wave block REQUIRES 4 waves/SIMD,
// so the hard VGPR cap is 128; launch_bounds(1024,4) tells the allocator to use all 128
// (round-15 lesson: bare launch_bounds(1024) defaulted to 64 regs -> spill, 26MB scratch).
// Each wave owns 2 elements/iter: ONE 16x128 A tile, rows 8e..8e+7 = [fwd, tan0..6].
// Abuf: [wid][row][k] bf16, 16B-block XOR swizzle: k-block kb stored at kb ^ (row&7).
// LDS ~145KB -> 1 block/CU. All per-iter LDS [wid]-indexed -> PHASE_FENCE only in loop.
__global__ __launch_bounds__(1024, 4) void kernA(
    const float* __restrict__ q, const float* __restrict__ dq, const float* __restrict__ ddq,
    const float* __restrict__ mW1, const float* __restrict__ mb1,
    const float* __restrict__ mb2, const float* __restrict__ mb3,
    const float* __restrict__ pW1, const float* __restrict__ pb1, const float* __restrict__ pw2,
    const unsigned* __restrict__ ws, float* __restrict__ out)
{
  __shared__ __align__(16) unsigned short Abuf[16][16][HID];    // 64KB, per-wave, reused for A'
  __shared__ __align__(16) uint4v W2lds[2048];                  // 32KB: 32 frags x 64 lanes
  __shared__ __align__(16) uint4v W3lds[512];                   // 8KB:  8 frags x 64 lanes
  __shared__ __align__(4)  unsigned short sbf[16][2][HID];      // 8KB, bf16 pairs
  __shared__ __align__(16) unsigned short rawb[16][2][CHOL][8]; // 14KB, bf16, [t][row]
  __shared__ float pW1s[DIM][HID+8];                            // shared pW1, padded
  __shared__ float b2s[HID];
  __shared__ float b3s[CHOL];
  __shared__ float Lbs[16][2][CHOL], dLss[16][2][CHOL], dfs[16][2][CHOL];
  __shared__ float gvp2[16][2][14];
  __shared__ float wbs[16][2][DIM], ubs[16][2][DIM], vss[16][2][DIM];

  const int tid  = threadIdx.x;
  const int wid  = tid>>6;
  const int lane = tid&63;
  const int g4 = lane>>4, c = lane&15;
  const int R = lane&15, r7 = lane&7;
  const int emt = lane>>5, s5 = lane&31;    // tail mapping: 32 lanes per element

  // ---- prologue staging (block-shared)
  if (tid < HID) b2s[tid] = mb2[tid];
  if (tid >= HID && tid < HID+CHOL) b3s[tid-HID] = mb3[tid-HID];
  for (int idx = tid; idx < DIM*HID; idx += 1024) pW1s[idx>>7][idx&127] = pW1[idx];
  for (int idx = tid; idx < 2048; idx += 1024) W2lds[idx] = ((const uint4v*)ws)[idx];
  if (tid < 512) W3lds[tid] = ((const uint4v*)(ws + 8192))[tid];

  // iteration-invariant weights in registers: lane owns hidden units 2*lane, 2*lane+1
  const int u0 = 2*lane, u1 = 2*lane+1;
  float w1a[DIM], w1b[DIM], pw1a[DIM], pw1b[DIM];
#pragma unroll
  for (int j=0;j<DIM;++j){
    w1a[j]=mW1[j*HID+u0];  w1b[j]=mW1[j*HID+u1];
    pw1a[j]=pW1[j*HID+u0]; pw1b[j]=pW1[j*HID+u1];
  }
  const float b1a=mb1[u0], b1b=mb1[u1];
  const float pba=pb1[u0], pbb=pb1[u1];
  const float spa=sp_f(pw2[u0]), spb=sp_f(pw2[u1]);

  __syncthreads();   // prologue only (shared staging)

  const int kb = lane>>2;          // (2*lane)>>3
  const int ko2 = (2*lane)&7;      // even slot in 8-elem block

  for (int it=0; it<ITER_A; ++it){
    const int ebase = (it*GRID_A + (int)blockIdx.x)*32 + wid*2;

    // ---- phase 1: layer 1 + tangent seeds + sb (paired b32 writes)
#pragma unroll
    for (int e=0;e<2;++e){
      const float* qp = q + (long)(ebase+e)*DIM;
      float qv[DIM];
#pragma unroll
      for (int j=0;j<DIM;++j) qv[j]=qp[j];
      const int R0 = 8*e;
      float z1a=b1a, z1b=b1b, zpa=pba, zpb=pbb;
#pragma unroll
      for (int j=0;j<DIM;++j){
        z1a=fmaf(qv[j],w1a[j],z1a);  z1b=fmaf(qv[j],w1b[j],z1b);
        zpa=fmaf(qv[j],pw1a[j],zpa); zpb=fmaf(qv[j],pw1b[j],zpb);
      }
      const float h1a=tanh_f(z1a), g1a=1.f-h1a*h1a;
      const float h1b=tanh_f(z1b), g1b=1.f-h1b*h1b;
      *(unsigned*)&Abuf[wid][R0][8*kb + ko2] = pk2(h1a, h1b);   // row&7==0: kb^0
#pragma unroll
      for (int j=0;j<DIM;++j)
        *(unsigned*)&Abuf[wid][R0+1+j][8*(kb^(1+j)) + ko2] = pk2(g1a*w1a[j], g1b*w1b[j]);
      *(unsigned*)&sbf[wid][e][u0] = pk2(sig_f(zpa)*spa, sig_f(zpb)*spb);
    }
    PHASE_FENCE();   // Abuf/sbf writes before A-frag reads

    // ---- read all A-fragments (Abuf then free for in-place A' overwrite)
    bf16x8 Af[4];
#pragma unroll
    for (int s=0;s<4;++s){
      const int blk = 8*((4*s+g4)^r7);
      Af[s] = *(const bf16x8*)&Abuf[wid][R][blk];
    }
    PHASE_FENCE();   // A-frag ds_reads issued before A' ds_writes (in-order DS pipe)

    // ---- fused layer-2 MFMA + h2 + A'-build, per col-tile t (4-reg live accumulator)
#pragma unroll
    for (int t=0;t<8;++t){
      f32x4 a0 = f32x4{0.f,0.f,0.f,0.f};
#pragma unroll
      for (int s=0;s<4;++s)
        a0 = __builtin_amdgcn_mfma_f32_16x16x32_bf16(Af[s], as_bf(W2lds[(s*8+t)*64 + lane]), a0, 0,0,0);
      const int col = 16*t+c;
      const int cb = col>>3, co = col&7;
      const float z2  = a0[0] + b2s[col];
      const float h2o = tanh_f(z2);                 // valid on even g4 (rows 0 and 8 = fwd)
      const float h2x = __shfl_xor(h2o, 16);
      const float h2  = (g4&1) ? h2x : h2o;
      const float g2  = 1.f - h2*h2;
#pragma unroll
      for (int reg=0;reg<4;++reg){
        const int Rr = 4*g4+reg;
        const int key = Rr&7;
        float v = g2*a0[reg];
        if (key==0) v = h2;
        Abuf[wid][Rr][8*(cb^key) + co] = f2b(v);
      }
    }
    PHASE_FENCE();   // A' writes before layer-3 reads

    // ---- layer 3 MFMA: [16 x 128] @ [128 x 32(pad of 28)], B from shared LDS
    f32x4 acc3[2];
    acc3[0]=f32x4{0.f,0.f,0.f,0.f}; acc3[1]=f32x4{0.f,0.f,0.f,0.f};
#pragma unroll
    for (int s=0;s<4;++s){
      const int blk = 8*((4*s+g4)^r7);
      bf16x8 A0 = *(const bf16x8*)&Abuf[wid][R][blk];
#pragma unroll
      for (int nt=0;nt<2;++nt)
        acc3[nt] = __builtin_amdgcn_mfma_f32_16x16x32_bf16(A0, as_bf(W3lds[(s*2+nt)*64+lane]), acc3[nt], 0,0,0);
    }

    // ---- gradV partials (VALU): element emt, slot s5<14: i=s5%7, half=s5/7 (paired reads)
    if (s5 < 14){
      const int iv = (s5<7)? s5 : s5-7;
      const int nb = (s5<7)? 0 : 64;
      float gp = 0.f;
#pragma unroll 8
      for (int nn=0; nn<32; ++nn){
        const unsigned sp2 = *(const unsigned*)&sbf[wid][emt][nb+2*nn];
        const float2 pw = *(const float2*)&pW1s[iv][nb+2*nn];
        gp = fmaf(pw.x, __uint_as_float(sp2<<16), gp);
        gp = fmaf(pw.y, __uint_as_float(sp2 & 0xFFFF0000u), gp);
      }
      gvp2[wid][emt][s5] = gp;
    }

    // ---- scatter raw to LDS: rawb[em][t][rows], b64 writes (4 rows packed)
    {
      const int em = g4>>1, rb = 4*(g4&1);
#pragma unroll
      for (int nt=0;nt<2;++nt){
        const int t = 16*nt+c;
        if (t < CHOL){
          uint2v p;
          p[0] = pk2(acc3[nt][0], acc3[nt][1]);
          p[1] = pk2(acc3[nt][2], acc3[nt][3]);
          *(uint2v*)&rawb[wid][em][t][rb] = p;
        }
      }
    }
    PHASE_FENCE();   // rawb/gvp2 writes before tail reads

    // ---- tail: element emt = lane>>5, 32 lanes each
    float dqv[DIM];
    {
      const float* dqp = dq + (long)(ebase+emt)*DIM;
#pragma unroll
      for (int j=0;j<DIM;++j) dqv[j]=dqp[j];
    }
    if (s5 < CHOL){
      const int t = s5;
      const uint4v r8 = *(const uint4v*)&rawb[wid][emt][t][0];   // rows 0..7, one b128
      const float rw0 = __uint_as_float(r8[0]<<16);
      const float rw1 = __uint_as_float(r8[0]&0xFFFF0000u);
      const float rw2 = __uint_as_float(r8[1]<<16);
      const float rw3 = __uint_as_float(r8[1]&0xFFFF0000u);
      const float rw4 = __uint_as_float(r8[2]<<16);
      const float rw5 = __uint_as_float(r8[2]&0xFFFF0000u);
      const float rw6 = __uint_as_float(r8[3]<<16);
      const float rw7 = __uint_as_float(r8[3]&0xFFFF0000u);
      const float e0 = rw0 + b3s[t];
      const bool dg = (t==0)|(t==2)|(t==5)|(t==9)|(t==14)|(t==20)|(t==27);
      const float Lv = dg ? sp_f(e0) : e0;
      const float df = dg ? sig_f(e0) : 1.f;
      float s_ = dqv[0]*rw1;
      s_ = fmaf(dqv[1], rw2, s_); s_ = fmaf(dqv[2], rw3, s_);
      s_ = fmaf(dqv[3], rw4, s_); s_ = fmaf(dqv[4], rw5, s_);
      s_ = fmaf(dqv[5], rw6, s_); s_ = fmaf(dqv[6], rw7, s_);
      Lbs[wid][emt][t]=Lv; dfs[wid][emt][t]=df; dLss[wid][emt][t]=df*s_;
    }
    PHASE_FENCE();   // Lbs/dfs/dLss writes before reads
    if (s5 < DIM){
      const int cc = s5;
      const float* ddqp = ddq + (long)(ebase+emt)*DIM;
      float wv=0.f, uv=0.f, vv=0.f;
#pragma unroll
      for (int r=0;r<DIM;++r){
        if (r>=cc){
          const int id=r*(r+1)/2+cc;
          const float Lrc = Lbs[wid][emt][id];
          wv=fmaf(Lrc,dqv[r],wv);
          uv=fmaf(Lrc,ddqp[r],uv);
          vv=fmaf(dLss[wid][emt][id],dqv[r],vv);
        }
      }
      wbs[wid][emt][cc]=wv; ubs[wid][emt][cc]=uv; vss[wid][emt][cc]=vv;
    }
    PHASE_FENCE();   // wbs/ubs/vss writes before reads
    if (s5 < DIM){
      const int i=s5;
      float t12=0.f;
#pragma unroll
      for (int c2=0;c2<DIM;++c2){
        if (c2<=i){
          const int id=i*(i+1)/2+c2;
          t12=fmaf(Lbs[wid][emt][id], ubs[wid][emt][c2]+vss[wid][emt][c2], t12);
          t12=fmaf(dLss[wid][emt][id], wbs[wid][emt][c2], t12);
        }
      }
      const int TRt[CHOL]={0,1,1,2,2,2,3,3,3,3,4,4,4,4,4,5,5,5,5,5,5,6,6,6,6,6,6,6};
      const int TCt[CHOL]={0,0,1,0,1,2,0,1,2,3,0,1,2,3,4,0,1,2,3,4,5,0,1,2,3,4,5,6};
      float t3=0.f;
#pragma unroll
      for (int t=0;t<CHOL;++t)
        t3=fmaf(b2f(rawb[wid][emt][t][1+i])*dfs[wid][emt][t], dqv[TRt[t]]*wbs[wid][emt][TCt[t]], t3);
      out[(long)(ebase+emt)*DIM + i] = t12 - t3 + gvp2[wid][emt][i] + gvp2[wid][emt][7+i];
    }
    PHASE_FENCE();   // iteration boundary: tail reads before next phase-1 overwrites
  }
}

// ---------------- Kernel B: damping, 8-wave blocks, dW2/dW3 in shared LDS (round-12 proven) --
__global__ __launch_bounds__(512, 2) void kernB(
    const float* __restrict__ q, const float* __restrict__ dq,
    const float* __restrict__ dW1, const float* __restrict__ db1,
    const float* __restrict__ db2, const float* __restrict__ db3,
    const unsigned* __restrict__ ws, float* __restrict__ out)
{
  __shared__ __align__(16) unsigned short AbufD[8][16][HID];   // 32KB, per-wave, reused for A'
  __shared__ __align__(16) uint4v dW2lds[2048];                // 32KB
  __shared__ __align__(16) uint4v dW3lds[512];                 // 8KB
  __shared__ float dW1s[2*DIM][HID];                           // 7KB (layer-1 weights)
  __shared__ float xsf[8][112+8], dsf[8][112+8];               // per-wave q/dq rows
  __shared__ float rawD[8][16][CHOL];
  __shared__ float LbD[8][16][CHOL];
  __shared__ float wdb[8][16][8];
  __shared__ float b2sD[HID];
  __shared__ float b3sD[CHOL];

  const int tid  = threadIdx.x;
  const int wid  = tid>>6;
  const int lane = tid&63;
  const int g4 = lane>>4, c = lane&15;
  const int R = lane&15, rkey = lane&7;
  const int eL = lane>>2, sub = lane&3;

  if (tid < HID) b2sD[tid] = db2[tid];
  if (tid >= HID && tid < HID+CHOL) b3sD[tid-HID] = db3[tid-HID];
  for (int idx = tid; idx < 2*DIM*HID; idx += 512) dW1s[idx>>7][idx&127] = dW1[idx];
  for (int idx = tid; idx < 2048; idx += 512) dW2lds[idx] = ((const uint4v*)(ws + 10240))[idx];
  for (int idx = tid; idx < 512;  idx += 512) dW3lds[idx] = ((const uint4v*)(ws + 18432))[idx];
  const float b1v0 = db1[lane], b1v1 = db1[lane+64];

  __syncthreads();   // prologue only

  for (int it=0; it<ITER_B; ++it){
    const int ebase = (it*GRID_B + (int)blockIdx.x)*128 + wid*16;

    // ---- stage x = [q,dq] rows (16 elements x 7, per wave)
    for (int idx=lane; idx<112; idx+=64){
      xsf[wid][idx] = q[(long)ebase*DIM + idx];
      dsf[wid][idx] = dq[(long)ebase*DIM + idx];
    }
    PHASE_FENCE();

    // ---- layer 1: z = [q,dq] @ dW1 + b1 ; stage h1 into swizzled Abuf
#pragma unroll
    for (int h=0; h<2; ++h){
      const int k = lane + 64*h;
      float z[16];
#pragma unroll
      for (int e=0;e<16;++e) z[e] = h ? b1v1 : b1v0;
#pragma unroll
      for (int j=0;j<DIM;++j){
        const float dj = dW1s[j][k & 127];
#pragma unroll
        for (int e=0;e<16;++e) z[e] = fmaf(xsf[wid][7*e+j], dj, z[e]);
      }
#pragma unroll
      for (int j=0;j<DIM;++j){
        const float dj = dW1s[DIM+j][k & 127];
#pragma unroll
        for (int e=0;e<16;++e) z[e] = fmaf(dsf[wid][7*e+j], dj, z[e]);
      }
      const int kb2 = k>>3, ko = k&7;
#pragma unroll
      for (int e=0;e<16;++e){
        AbufD[wid][e][8*(kb2^(e&7)) + ko] = f2b(tanh_f(z[e]));
      }
    }
    PHASE_FENCE();   // Abuf writes before layer-2 reads

    // ---- layer 2 MFMA: [16 x 128] @ [128 x 128]
    f32x4 acc[8];
#pragma unroll
    for (int b=0;b<8;++b) acc[b] = f32x4{0.f,0.f,0.f,0.f};
#pragma unroll
    for (int s=0;s<4;++s){
      const int blk = 8*((4*s+g4)^rkey);
      bf16x8 A0 = *(const bf16x8*)&AbufD[wid][R][blk];
#pragma unroll
      for (int t=0;t<8;++t)
        acc[t] = __builtin_amdgcn_mfma_f32_16x16x32_bf16(A0, as_bf(dW2lds[(s*8+t)*64+lane]), acc[t], 0,0,0);
    }
    PHASE_FENCE();   // Abuf reads before A' overwrite

    // ---- h2 = tanh(z2), restage A' (C layout: row e = 4*g4+reg, col = 16t+c)
#pragma unroll
    for (int t=0;t<8;++t){
      const int col = 16*t+c;
      const int cb = col>>3, co = col&7;
#pragma unroll
      for (int reg=0;reg<4;++reg){
        const int e = 4*g4+reg;
        const float h2 = tanh_f(acc[t][reg] + b2sD[col]);
        AbufD[wid][e][8*(cb^(e&7)) + co] = f2b(h2);
      }
    }
    PHASE_FENCE();   // A' writes before layer-3 reads

    // ---- layer 3 MFMA: [16 x 128] @ [128 x 32(pad of 28)]
    f32x4 acc3[2];
    acc3[0]=f32x4{0.f,0.f,0.f,0.f}; acc3[1]=f32x4{0.f,0.f,0.f,0.f};
#pragma unroll
    for (int s=0;s<4;++s){
      const int blk = 8*((4*s+g4)^rkey);
      bf16x8 A0 = *(const bf16x8*)&AbufD[wid][R][blk];
#pragma unroll
      for (int nt=0;nt<2;++nt)
        acc3[nt] = __builtin_amdgcn_mfma_f32_16x16x32_bf16(A0, as_bf(dW3lds[(s*2+nt)*64+lane]), acc3[nt], 0,0,0);
    }

    // ---- scatter raw
#pragma unroll
    for (int nt=0;nt<2;++nt){
      const int t = 16*nt+c;
      if (t < CHOL){
#pragma unroll
        for (int reg=0;reg<4;++reg) rawD[wid][4*g4+reg][t] = acc3[nt][reg];
      }
    }
    PHASE_FENCE();   // rawD writes before L-build reads

    // ---- build L (softplus diagonal): 4 lanes/element, 7 entries each
#pragma unroll
    for (int m=0;m<7;++m){
      const int t = 7*sub + m;
      const float e0 = rawD[wid][eL][t] + b3sD[t];
      const bool dg = (t==0)|(t==2)|(t==5)|(t==9)|(t==14)|(t==20)|(t==27);
      LbD[wid][eL][t] = dg ? sp_f(e0) : e0;
    }
    PHASE_FENCE();

    // ---- w = L^T dq : lane covers c = sub, sub+4
    for (int cc = sub; cc < DIM; cc += 4){
      float wv = 0.f;
      for (int r = cc; r < DIM; ++r)
        wv = fmaf(LbD[wid][eL][r*(r+1)/2 + cc], dsf[wid][7*eL + r], wv);
      wdb[wid][eL][cc] = wv;
    }
    PHASE_FENCE();

    // ---- tau += L w : lane covers i = sub, sub+4
    for (int i0 = sub; i0 < DIM; i0 += 4){
      float td = 0.f;
      for (int cc = 0; cc <= i0; ++cc)
        td = fmaf(LbD[wid][eL][i0*(i0+1)/2 + cc], wdb[wid][eL][cc], td);
      out[(long)(ebase+eL)*DIM + i0] += td;
    }
    PHASE_FENCE();   // tail reads before next-iter overwrites
  }
}

extern "C" void kernel_launch(void* const* d_in, const int* in_sizes, int n_in,
                              void* d_out, int out_size, void* d_ws, size_t ws_size,
                              hipStream_t stream) {
  const float* q   = (const float*)d_in[0];
  const float* dq  = (const float*)d_in[1];
  const float* ddq = (const float*)d_in[2];
  const float* mW1 = (const float*)d_in[3];
  const float* mb1 = (const float*)d_in[4];
  const float* mW2 = (const float*)d_in[5];
  const float* mb2 = (const float*)d_in[6];
  const float* mW3 = (const float*)d_in[7];
  const float* mb3 = (const float*)d_in[8];
  const float* dW1 = (const float*)d_in[9];
  const float* db1 = (const float*)d_in[10];
  const float* dW2 = (const float*)d_in[11];
  const float* db2 = (const float*)d_in[12];
  const float* dW3 = (const float*)d_in[13];
  const float* db3 = (const float*)d_in[14];
  const float* pW1 = (const float*)d_in[15];
  const float* pb1 = (const float*)d_in[16];
  const float* pw2 = (const float*)d_in[17];
  float* out = (float*)d_out;
  unsigned* wsu = (unsigned*)d_ws;

  hipLaunchKernelGGL(setup_frags, dim3(80), dim3(256), 0, stream, mW2, mW3, dW2, dW3, wsu);
  hipLaunchKernelGGL(kernA, dim3(GRID_A), dim3(1024), 0, stream,
                     q, dq, ddq, mW1, mb1, mb2, mb3, pW1, pb1, pw2, (const unsigned*)wsu, out);
  hipLaunchKernelGGL(kernB, dim3(GRID_B), dim3(512), 0, stream,
                     q, dq, dW1, db1, db2, db3, (const unsigned*)wsu, out);
}

// Round 17
// 223.000 us; speedup vs baseline: 1.1823x; 1.1823x over previous
//
#include <hip/hip_runtime.h>

#define DIM 7
#define HID 128
#define CHOL 28

#define GRID_A 512
#define ITER_A 8           // 512 blocks * 16 waves * 2 elem * 8 iter = 131072
#define GRID_B 256
#define ITER_B 4           // 256 blocks * 8 waves * 16 elem * 4 iter = 131072

// sched_barrier mask: ALU|VALU|SALU|MFMA|VMEM may cross; DS blocked (per-wave phase ordering).
#define PHASE_FENCE() __builtin_amdgcn_sched_barrier(0x7F)

typedef float    f32x4  __attribute__((ext_vector_type(4)));
typedef short    bf16x8 __attribute__((ext_vector_type(8)));
typedef unsigned uint4v __attribute__((ext_vector_type(4)));
typedef unsigned uint2v __attribute__((ext_vector_type(2)));

__device__ __forceinline__ float rcp_f(float x){ return __builtin_amdgcn_rcpf(x); }
__device__ __forceinline__ float tanh_f(float x){ float e=__expf(2.f*x); return 1.f - 2.f*rcp_f(e+1.f); }
__device__ __forceinline__ float sig_f(float x){ return rcp_f(1.f+__expf(-x)); }
__device__ __forceinline__ float sp_f(float x){ return fmaxf(x,0.f) + __logf(1.f+__expf(-fabsf(x))); }

__device__ __forceinline__ unsigned short f2b(float v){
  unsigned u = __float_as_uint(v);
  u += 0x7FFFu + ((u>>16)&1u);          // RNE to bf16
  return (unsigned short)(u>>16);
}
// pack two f32 -> (bf16(a) | bf16(b)<<16), RNE
__device__ __forceinline__ unsigned pk2(float a, float b){
  unsigned ua = __float_as_uint(a), ub = __float_as_uint(b);
  ua += 0x7FFFu + ((ua>>16)&1u);
  ub += 0x7FFFu + ((ub>>16)&1u);
  return (ua>>16) | (ub & 0xFFFF0000u);
}
__device__ __forceinline__ float b2f(unsigned short v){
  return __uint_as_float(((unsigned)v)<<16);
}
__device__ __forceinline__ bf16x8 as_bf(uint4v u){ union { uint4v a; bf16x8 f; } x; x.a=u; return x.f; }

// ---- ws layout (u32): [0,8192) W2frag ; [8192,10240) W3frag ; [10240,18432) dW2frag ;
//                       [18432,20480) dW3frag   (80 KB total)
// frag order: u32 idx = (frag_id*64 + lane)*4 + i2 ; B[k][col], k = 32s+8*(l>>4)+2*i2(+1), col = 16t+(l&15)
// (A-frags use the SAME (group,elem)->k map, so layer-2/3 are correct for any HW intra-lane k order.)
__global__ void setup_frags(const float* __restrict__ mW2, const float* __restrict__ mW3,
                            const float* __restrict__ dW2, const float* __restrict__ dW3,
                            unsigned* __restrict__ ws){
  int idx = blockIdx.x*256 + threadIdx.x;
  if (idx < 8192) {
    int i2 = idx&3, f = idx>>2, l = f&63, st = f>>6;
    int s = st>>3, t = st&7;
    int k = 32*s + 8*(l>>4) + 2*i2, col = 16*t + (l&15);
    ws[idx] = pk2(mW2[k*HID+col], mW2[(k+1)*HID+col]);
  } else if (idx < 10240) {
    int j = idx-8192; int i2=j&3, f=j>>2, l=f&63, st=f>>6;
    int s = st>>1, t = st&1;
    int k = 32*s + 8*(l>>4) + 2*i2, col = 16*t + (l&15);
    float v0 = (col<CHOL) ? mW3[k*CHOL+col] : 0.f;
    float v1 = (col<CHOL) ? mW3[(k+1)*CHOL+col] : 0.f;
    ws[idx] = pk2(v0,v1);
  } else if (idx < 18432) {
    int j = idx-10240; int i2=j&3, f=j>>2, l=f&63, st=f>>6;
    int s = st>>3, t = st&7;
    int k = 32*s + 8*(l>>4) + 2*i2, col = 16*t + (l&15);
    ws[idx] = pk2(dW2[k*HID+col], dW2[(k+1)*HID+col]);
  } else if (idx < 20480) {
    int j = idx-18432; int i2=j&3, f=j>>2, l=f&63, st=f>>6;
    int s = st>>1, t = st&1;
    int k = 32*s + 8*(l>>4) + 2*i2, col = 16*t + (l&15);
    float v0 = (col<CHOL) ? dW3[k*CHOL+col] : 0.f;
    float v1 = (col<CHOL) ? dW3[(k+1)*CHOL+col] : 0.f;
    ws[idx] = pk2(v0,v1);
  }
}

// ---------------- Kernel A: ONE 16-wave block per CU; ALL weights in shared LDS -------------
// 16 waves co-resident -> 4 waves/SIMD. amdgpu_waves_per_eu(4,4) pins the allocator to the
// 128-VGPR budget (round-15/16 lesson: launch_bounds variants kept choosing 64 -> spill).
// Layer-1 weights (w1, pw1) read from LDS as b64 pairs -> per-wave register demand ~80.
// Each wave owns 2 elements/iter: ONE 16x128 A tile, rows 8e..8e+7 = [fwd, tan0..6].
// Abuf: [wid][row][k] bf16, 16B-block XOR swizzle: k-block kb stored at kb ^ (row&7).
// LDS ~152KB -> 1 block/CU. All per-iter LDS [wid]-indexed -> PHASE_FENCE only in loop.
__global__ __attribute__((amdgpu_flat_work_group_size(1024,1024)))
__attribute__((amdgpu_waves_per_eu(4,4)))
void kernA(
    const float* __restrict__ q, const float* __restrict__ dq, const float* __restrict__ ddq,
    const float* __restrict__ mW1, const float* __restrict__ mb1,
    const float* __restrict__ mb2, const float* __restrict__ mb3,
    const float* __restrict__ pW1, const float* __restrict__ pb1, const float* __restrict__ pw2,
    const unsigned* __restrict__ ws, float* __restrict__ out)
{
  __shared__ __align__(16) unsigned short Abuf[16][16][HID];    // 64KB, per-wave, reused for A'
  __shared__ __align__(16) uint4v W2lds[2048];                  // 32KB: 32 frags x 64 lanes
  __shared__ __align__(16) uint4v W3lds[512];                   // 8KB:  8 frags x 64 lanes
  __shared__ __align__(4)  unsigned short sbf[16][2][HID];      // 8KB, bf16 pairs
  __shared__ __align__(16) unsigned short rawb[16][2][CHOL][8]; // 14KB, bf16, [t][row]
  __shared__ float pW1s[DIM][HID+8];                            // shared pW1, padded
  __shared__ __align__(8) float w1s[DIM][HID];                  // 3.5KB: layer-1 weights
  __shared__ float b2s[HID];
  __shared__ float b3s[CHOL];
  __shared__ float Lbs[16][2][CHOL], dLss[16][2][CHOL], dfs[16][2][CHOL];
  __shared__ float gvp2[16][2][14];
  __shared__ float wbs[16][2][DIM], ubs[16][2][DIM], vss[16][2][DIM];

  const int tid  = threadIdx.x;
  const int wid  = tid>>6;
  const int lane = tid&63;
  const int g4 = lane>>4, c = lane&15;
  const int R = lane&15, r7 = lane&7;
  const int emt = lane>>5, s5 = lane&31;    // tail mapping: 32 lanes per element

  // ---- prologue staging (block-shared)
  if (tid < HID) b2s[tid] = mb2[tid];
  if (tid >= HID && tid < HID+CHOL) b3s[tid-HID] = mb3[tid-HID];
  for (int idx = tid; idx < DIM*HID; idx += 1024){
    pW1s[idx>>7][idx&127] = pW1[idx];
    w1s[idx>>7][idx&127]  = mW1[idx];
  }
  for (int idx = tid; idx < 2048; idx += 1024) W2lds[idx] = ((const uint4v*)ws)[idx];
  if (tid < 512) W3lds[tid] = ((const uint4v*)(ws + 8192))[tid];

  // iteration-invariant per-lane constants: lane owns hidden units 2*lane, 2*lane+1
  const int u0 = 2*lane;
  const float b1a=mb1[u0], b1b=mb1[u0+1];
  const float pba=pb1[u0], pbb=pb1[u0+1];
  const float spa=sp_f(pw2[u0]), spb=sp_f(pw2[u0+1]);

  __syncthreads();   // prologue only (shared staging)

  const int kb = lane>>2;          // (2*lane)>>3
  const int ko2 = (2*lane)&7;      // even slot in 8-elem block

  for (int it=0; it<ITER_A; ++it){
    const int ebase = (it*GRID_A + (int)blockIdx.x)*32 + wid*2;

    // ---- phase 1: layer 1 + tangent seeds + sb (weights from LDS, paired b32 writes)
#pragma unroll
    for (int e=0;e<2;++e){
      const float* qp = q + (long)(ebase+e)*DIM;
      float qv[DIM];
#pragma unroll
      for (int j=0;j<DIM;++j) qv[j]=qp[j];
      const int R0 = 8*e;
      float w1r0[DIM], w1r1[DIM];
      float z1a=b1a, z1b=b1b, zpa=pba, zpb=pbb;
#pragma unroll
      for (int j=0;j<DIM;++j){
        const float2 wj = *(const float2*)&w1s[j][u0];
        const float2 pj = *(const float2*)&pW1s[j][u0];
        w1r0[j]=wj.x; w1r1[j]=wj.y;
        z1a=fmaf(qv[j],wj.x,z1a);  z1b=fmaf(qv[j],wj.y,z1b);
        zpa=fmaf(qv[j],pj.x,zpa);  zpb=fmaf(qv[j],pj.y,zpb);
      }
      const float h1a=tanh_f(z1a), g1a=1.f-h1a*h1a;
      const float h1b=tanh_f(z1b), g1b=1.f-h1b*h1b;
      *(unsigned*)&Abuf[wid][R0][8*kb + ko2] = pk2(h1a, h1b);   // row&7==0: kb^0
#pragma unroll
      for (int j=0;j<DIM;++j)
        *(unsigned*)&Abuf[wid][R0+1+j][8*(kb^(1+j)) + ko2] = pk2(g1a*w1r0[j], g1b*w1r1[j]);
      *(unsigned*)&sbf[wid][e][u0] = pk2(sig_f(zpa)*spa, sig_f(zpb)*spb);
    }
    PHASE_FENCE();   // Abuf/sbf writes before A-frag reads

    // ---- read all A-fragments (Abuf then free for in-place A' overwrite)
    bf16x8 Af[4];
#pragma unroll
    for (int s=0;s<4;++s){
      const int blk = 8*((4*s+g4)^r7);
      Af[s] = *(const bf16x8*)&Abuf[wid][R][blk];
    }
    PHASE_FENCE();   // A-frag ds_reads issued before A' ds_writes (in-order DS pipe)

    // ---- fused layer-2 MFMA + h2 + A'-build, per col-tile t (4-reg live accumulator)
#pragma unroll
    for (int t=0;t<8;++t){
      f32x4 a0 = f32x4{0.f,0.f,0.f,0.f};
#pragma unroll
      for (int s=0;s<4;++s)
        a0 = __builtin_amdgcn_mfma_f32_16x16x32_bf16(Af[s], as_bf(W2lds[(s*8+t)*64 + lane]), a0, 0,0,0);
      const int col = 16*t+c;
      const int cb = col>>3, co = col&7;
      const float z2  = a0[0] + b2s[col];
      const float h2o = tanh_f(z2);                 // valid on even g4 (rows 0 and 8 = fwd)
      const float h2x = __shfl_xor(h2o, 16);
      const float h2  = (g4&1) ? h2x : h2o;
      const float g2  = 1.f - h2*h2;
#pragma unroll
      for (int reg=0;reg<4;++reg){
        const int Rr = 4*g4+reg;
        const int key = Rr&7;
        float v = g2*a0[reg];
        if (key==0) v = h2;
        Abuf[wid][Rr][8*(cb^key) + co] = f2b(v);
      }
    }
    PHASE_FENCE();   // A' writes before layer-3 reads

    // ---- layer 3 MFMA: [16 x 128] @ [128 x 32(pad of 28)], B from shared LDS
    f32x4 acc3[2];
    acc3[0]=f32x4{0.f,0.f,0.f,0.f}; acc3[1]=f32x4{0.f,0.f,0.f,0.f};
#pragma unroll
    for (int s=0;s<4;++s){
      const int blk = 8*((4*s+g4)^r7);
      bf16x8 A0 = *(const bf16x8*)&Abuf[wid][R][blk];
#pragma unroll
      for (int nt=0;nt<2;++nt)
        acc3[nt] = __builtin_amdgcn_mfma_f32_16x16x32_bf16(A0, as_bf(W3lds[(s*2+nt)*64+lane]), acc3[nt], 0,0,0);
    }

    // ---- gradV partials (VALU): element emt, slot s5<14: i=s5%7, half=s5/7 (paired reads)
    if (s5 < 14){
      const int iv = (s5<7)? s5 : s5-7;
      const int nb = (s5<7)? 0 : 64;
      float gp = 0.f;
#pragma unroll 8
      for (int nn=0; nn<32; ++nn){
        const unsigned sp2 = *(const unsigned*)&sbf[wid][emt][nb+2*nn];
        const float2 pw = *(const float2*)&pW1s[iv][nb+2*nn];
        gp = fmaf(pw.x, __uint_as_float(sp2<<16), gp);
        gp = fmaf(pw.y, __uint_as_float(sp2 & 0xFFFF0000u), gp);
      }
      gvp2[wid][emt][s5] = gp;
    }

    // ---- scatter raw to LDS: rawb[em][t][rows], b64 writes (4 rows packed)
    {
      const int em = g4>>1, rb = 4*(g4&1);
#pragma unroll
      for (int nt=0;nt<2;++nt){
        const int t = 16*nt+c;
        if (t < CHOL){
          uint2v p;
          p[0] = pk2(acc3[nt][0], acc3[nt][1]);
          p[1] = pk2(acc3[nt][2], acc3[nt][3]);
          *(uint2v*)&rawb[wid][em][t][rb] = p;
        }
      }
    }
    PHASE_FENCE();   // rawb/gvp2 writes before tail reads

    // ---- tail: element emt = lane>>5, 32 lanes each
    float dqv[DIM];
    {
      const float* dqp = dq + (long)(ebase+emt)*DIM;
#pragma unroll
      for (int j=0;j<DIM;++j) dqv[j]=dqp[j];
    }
    if (s5 < CHOL){
      const int t = s5;
      const uint4v r8 = *(const uint4v*)&rawb[wid][emt][t][0];   // rows 0..7, one b128
      const float rw0 = __uint_as_float(r8[0]<<16);
      const float rw1 = __uint_as_float(r8[0]&0xFFFF0000u);
      const float rw2 = __uint_as_float(r8[1]<<16);
      const float rw3 = __uint_as_float(r8[1]&0xFFFF0000u);
      const float rw4 = __uint_as_float(r8[2]<<16);
      const float rw5 = __uint_as_float(r8[2]&0xFFFF0000u);
      const float rw6 = __uint_as_float(r8[3]<<16);
      const float rw7 = __uint_as_float(r8[3]&0xFFFF0000u);
      const float e0 = rw0 + b3s[t];
      const bool dg = (t==0)|(t==2)|(t==5)|(t==9)|(t==14)|(t==20)|(t==27);
      const float Lv = dg ? sp_f(e0) : e0;
      const float df = dg ? sig_f(e0) : 1.f;
      float s_ = dqv[0]*rw1;
      s_ = fmaf(dqv[1], rw2, s_); s_ = fmaf(dqv[2], rw3, s_);
      s_ = fmaf(dqv[3], rw4, s_); s_ = fmaf(dqv[4], rw5, s_);
      s_ = fmaf(dqv[5], rw6, s_); s_ = fmaf(dqv[6], rw7, s_);
      Lbs[wid][emt][t]=Lv; dfs[wid][emt][t]=df; dLss[wid][emt][t]=df*s_;
    }
    PHASE_FENCE();   // Lbs/dfs/dLss writes before reads
    if (s5 < DIM){
      const int cc = s5;
      const float* ddqp = ddq + (long)(ebase+emt)*DIM;
      float wv=0.f, uv=0.f, vv=0.f;
#pragma unroll
      for (int r=0;r<DIM;++r){
        if (r>=cc){
          const int id=r*(r+1)/2+cc;
          const float Lrc = Lbs[wid][emt][id];
          wv=fmaf(Lrc,dqv[r],wv);
          uv=fmaf(Lrc,ddqp[r],uv);
          vv=fmaf(dLss[wid][emt][id],dqv[r],vv);
        }
      }
      wbs[wid][emt][cc]=wv; ubs[wid][emt][cc]=uv; vss[wid][emt][cc]=vv;
    }
    PHASE_FENCE();   // wbs/ubs/vss writes before reads
    if (s5 < DIM){
      const int i=s5;
      float t12=0.f;
#pragma unroll
      for (int c2=0;c2<DIM;++c2){
        if (c2<=i){
          const int id=i*(i+1)/2+c2;
          t12=fmaf(Lbs[wid][emt][id], ubs[wid][emt][c2]+vss[wid][emt][c2], t12);
          t12=fmaf(dLss[wid][emt][id], wbs[wid][emt][c2], t12);
        }
      }
      const int TRt[CHOL]={0,1,1,2,2,2,3,3,3,3,4,4,4,4,4,5,5,5,5,5,5,6,6,6,6,6,6,6};
      const int TCt[CHOL]={0,0,1,0,1,2,0,1,2,3,0,1,2,3,4,0,1,2,3,4,5,0,1,2,3,4,5,6};
      float t3=0.f;
#pragma unroll
      for (int t=0;t<CHOL;++t)
        t3=fmaf(b2f(rawb[wid][emt][t][1+i])*dfs[wid][emt][t], dqv[TRt[t]]*wbs[wid][emt][TCt[t]], t3);
      out[(long)(ebase+emt)*DIM + i] = t12 - t3 + gvp2[wid][emt][i] + gvp2[wid][emt][7+i];
    }
    PHASE_FENCE();   // iteration boundary: tail reads before next phase-1 overwrites
  }
}

// ---------------- Kernel B: damping, 8-wave blocks, dW2/dW3 in shared LDS (round-12 proven) --
__global__ __launch_bounds__(512, 2) void kernB(
    const float* __restrict__ q, const float* __restrict__ dq,
    const float* __restrict__ dW1, const float* __restrict__ db1,
    const float* __restrict__ db2, const float* __restrict__ db3,
    const unsigned* __restrict__ ws, float* __restrict__ out)
{
  __shared__ __align__(16) unsigned short AbufD[8][16][HID];   // 32KB, per-wave, reused for A'
  __shared__ __align__(16) uint4v dW2lds[2048];                // 32KB
  __shared__ __align__(16) uint4v dW3lds[512];                 // 8KB
  __shared__ float dW1s[2*DIM][HID];                           // 7KB (layer-1 weights)
  __shared__ float xsf[8][112+8], dsf[8][112+8];               // per-wave q/dq rows
  __shared__ float rawD[8][16][CHOL];
  __shared__ float LbD[8][16][CHOL];
  __shared__ float wdb[8][16][8];
  __shared__ float b2sD[HID];
  __shared__ float b3sD[CHOL];

  const int tid  = threadIdx.x;
  const int wid  = tid>>6;
  const int lane = tid&63;
  const int g4 = lane>>4, c = lane&15;
  const int R = lane&15, rkey = lane&7;
  const int eL = lane>>2, sub = lane&3;

  if (tid < HID) b2sD[tid] = db2[tid];
  if (tid >= HID && tid < HID+CHOL) b3sD[tid-HID] = db3[tid-HID];
  for (int idx = tid; idx < 2*DIM*HID; idx += 512) dW1s[idx>>7][idx&127] = dW1[idx];
  for (int idx = tid; idx < 2048; idx += 512) dW2lds[idx] = ((const uint4v*)(ws + 10240))[idx];
  for (int idx = tid; idx < 512;  idx += 512) dW3lds[idx] = ((const uint4v*)(ws + 18432))[idx];
  const float b1v0 = db1[lane], b1v1 = db1[lane+64];

  __syncthreads();   // prologue only

  for (int it=0; it<ITER_B; ++it){
    const int ebase = (it*GRID_B + (int)blockIdx.x)*128 + wid*16;

    // ---- stage x = [q,dq] rows (16 elements x 7, per wave)
    for (int idx=lane; idx<112; idx+=64){
      xsf[wid][idx] = q[(long)ebase*DIM + idx];
      dsf[wid][idx] = dq[(long)ebase*DIM + idx];
    }
    PHASE_FENCE();

    // ---- layer 1: z = [q,dq] @ dW1 + b1 ; stage h1 into swizzled Abuf
#pragma unroll
    for (int h=0; h<2; ++h){
      const int k = lane + 64*h;
      float z[16];
#pragma unroll
      for (int e=0;e<16;++e) z[e] = h ? b1v1 : b1v0;
#pragma unroll
      for (int j=0;j<DIM;++j){
        const float dj = dW1s[j][k & 127];
#pragma unroll
        for (int e=0;e<16;++e) z[e] = fmaf(xsf[wid][7*e+j], dj, z[e]);
      }
#pragma unroll
      for (int j=0;j<DIM;++j){
        const float dj = dW1s[DIM+j][k & 127];
#pragma unroll
        for (int e=0;e<16;++e) z[e] = fmaf(dsf[wid][7*e+j], dj, z[e]);
      }
      const int kb2 = k>>3, ko = k&7;
#pragma unroll
      for (int e=0;e<16;++e){
        AbufD[wid][e][8*(kb2^(e&7)) + ko] = f2b(tanh_f(z[e]));
      }
    }
    PHASE_FENCE();   // Abuf writes before layer-2 reads

    // ---- layer 2 MFMA: [16 x 128] @ [128 x 128]
    f32x4 acc[8];
#pragma unroll
    for (int b=0;b<8;++b) acc[b] = f32x4{0.f,0.f,0.f,0.f};
#pragma unroll
    for (int s=0;s<4;++s){
      const int blk = 8*((4*s+g4)^rkey);
      bf16x8 A0 = *(const bf16x8*)&AbufD[wid][R][blk];
#pragma unroll
      for (int t=0;t<8;++t)
        acc[t] = __builtin_amdgcn_mfma_f32_16x16x32_bf16(A0, as_bf(dW2lds[(s*8+t)*64+lane]), acc[t], 0,0,0);
    }
    PHASE_FENCE();   // Abuf reads before A' overwrite

    // ---- h2 = tanh(z2), restage A' (C layout: row e = 4*g4+reg, col = 16t+c)
#pragma unroll
    for (int t=0;t<8;++t){
      const int col = 16*t+c;
      const int cb = col>>3, co = col&7;
#pragma unroll
      for (int reg=0;reg<4;++reg){
        const int e = 4*g4+reg;
        const float h2 = tanh_f(acc[t][reg] + b2sD[col]);
        AbufD[wid][e][8*(cb^(e&7)) + co] = f2b(h2);
      }
    }
    PHASE_FENCE();   // A' writes before layer-3 reads

    // ---- layer 3 MFMA: [16 x 128] @ [128 x 32(pad of 28)]
    f32x4 acc3[2];
    acc3[0]=f32x4{0.f,0.f,0.f,0.f}; acc3[1]=f32x4{0.f,0.f,0.f,0.f};
#pragma unroll
    for (int s=0;s<4;++s){
      const int blk = 8*((4*s+g4)^rkey);
      bf16x8 A0 = *(const bf16x8*)&AbufD[wid][R][blk];
#pragma unroll
      for (int nt=0;nt<2;++nt)
        acc3[nt] = __builtin_amdgcn_mfma_f32_16x16x32_bf16(A0, as_bf(dW3lds[(s*2+nt)*64+lane]), acc3[nt], 0,0,0);
    }

    // ---- scatter raw
#pragma unroll
    for (int nt=0;nt<2;++nt){
      const int t = 16*nt+c;
      if (t < CHOL){
#pragma unroll
        for (int reg=0;reg<4;++reg) rawD[wid][4*g4+reg][t] = acc3[nt][reg];
      }
    }
    PHASE_FENCE();   // rawD writes before L-build reads

    // ---- build L (softplus diagonal): 4 lanes/element, 7 entries each
#pragma unroll
    for (int m=0;m<7;++m){
      const int t = 7*sub + m;
      const float e0 = rawD[wid][eL][t] + b3sD[t];
      const bool dg = (t==0)|(t==2)|(t==5)|(t==9)|(t==14)|(t==20)|(t==27);
      LbD[wid][eL][t] = dg ? sp_f(e0) : e0;
    }
    PHASE_FENCE();

    // ---- w = L^T dq : lane covers c = sub, sub+4
    for (int cc = sub; cc < DIM; cc += 4){
      float wv = 0.f;
      for (int r = cc; r < DIM; ++r)
        wv = fmaf(LbD[wid][eL][r*(r+1)/2 + cc], dsf[wid][7*eL + r], wv);
      wdb[wid][eL][cc] = wv;
    }
    PHASE_FENCE();

    // ---- tau += L w : lane covers i = sub, sub+4
    for (int i0 = sub; i0 < DIM; i0 += 4){
      float td = 0.f;
      for (int cc = 0; cc <= i0; ++cc)
        td = fmaf(LbD[wid][eL][i0*(i0+1)/2 + cc], wdb[wid][eL][cc], td);
      out[(long)(ebase+eL)*DIM + i0] += td;
    }
    PHASE_FENCE();   // tail reads before next-iter overwrites
  }
}

extern "C" void kernel_launch(void* const* d_in, const int* in_sizes, int n_in,
                              void* d_out, int out_size, void* d_ws, size_t ws_size,
                              hipStream_t stream) {
  const float* q   = (const float*)d_in[0];
  const float* dq  = (const float*)d_in[1];
  const float* ddq = (const float*)d_in[2];
  const float* mW1 = (const float*)d_in[3];
  const float* mb1 = (const float*)d_in[4];
  const float* mW2 = (const float*)d_in[5];
  const float* mb2 = (const float*)d_in[6];
  const float* mW3 = (const float*)d_in[7];
  const float* mb3 = (const float*)d_in[8];
  const float* dW1 = (const float*)d_in[9];
  const float* db1 = (const float*)d_in[10];
  const float* dW2 = (const float*)d_in[11];
  const float* db2 = (const float*)d_in[12];
  const float* dW3 = (const float*)d_in[13];
  const float* db3 = (const float*)d_in[14];
  const float* pW1 = (const float*)d_in[15];
  const float* pb1 = (const float*)d_in[16];
  const float* pw2 = (const float*)d_in[17];
  float* out = (float*)d_out;
  unsigned* wsu = (unsigned*)d_ws;

  hipLaunchKernelGGL(setup_frags, dim3(80), dim3(256), 0, stream, mW2, mW3, dW2, dW3, wsu);
  hipLaunchKernelGGL(kernA, dim3(GRID_A), dim3(1024), 0, stream,
                     q, dq, ddq, mW1, mb1, mb2, mb3, pW1, pb1, pw2, (const unsigned*)wsu, out);
  hipLaunchKernelGGL(kernB, dim3(GRID_B), dim3(512), 0, stream,
                     q, dq, dW1, db1, db2, db3, (const unsigned*)wsu, out);
}